// Round 9
// baseline (335.314 us; speedup 1.0000x reference)
//
#include <hip/hip_runtime.h>
#include <hip/hip_bf16.h>
#include <stdint.h>

// Problem constants (fixed by the reference setup_inputs)
#define BATCH  16384
#define D_IN   1024
#define M_HID  4096
#define R_LORA 16
#define SCALING 2.0f   // ALPHA/R = 32/16

// R9: break the ~22.4 B/cyc/CU VMEM streaming wall by doubling FLOP per
// W-byte (64 -> 128). x is int8 (per-row scale, exact-in-bf16 expansion) so a
// 128-row strip fits 128 KiB LDS; each wave covers 128 rows x 64 n. Grid =
// 128 strips x 2 n-halves = 256 blocks; blockIdx parity == XCD parity pins a
// fixed 4 MB W-slice per XCD (L2-resident). W stays bf16 (no new quant or
// MFMA-layout risk). Evidence for the wall: m13/m97/m103/ours/hipBLASLt all
// stream 21-26 B/cyc/CU; winners differ only in FLOP/staged-byte.
#define STRIP    128
#define NTHREADS 512

typedef __bf16 bf16x8 __attribute__((ext_vector_type(8)));
typedef float  f32x16 __attribute__((ext_vector_type(16)));
typedef float  nfloat4 __attribute__((ext_vector_type(4)));

__device__ __forceinline__ unsigned short f2bf(float f) {
    union { float f; unsigned int u; } c; c.f = f;
    unsigned int u = c.u;
    return (unsigned short)((u + 0x7FFFu + ((u >> 16) & 1u)) >> 16);
}

// 8 x i8 -> 8 x bf16 (integer-valued; |v|<=127 is exact in bf16, low f32 bits
// zero so truncating pack is exact). ~3.5 VALU/elem, overlaps MFMA pipe.
__device__ __forceinline__ bf16x8 expand8(int lo, int hi) {
    union { bf16x8 v; unsigned u[4]; } o;
#pragma unroll
    for (int d = 0; d < 2; ++d) {
        int src = d ? hi : lo;
        float f0 = (float)((src << 24) >> 24);
        float f1 = (float)((src << 16) >> 24);
        float f2 = (float)((src << 8) >> 24);
        float f3 = (float)(src >> 24);
        unsigned u0 = __float_as_uint(f0), u1 = __float_as_uint(f1);
        unsigned u2 = __float_as_uint(f2), u3 = __float_as_uint(f3);
        o.u[d * 2 + 0] = (u0 >> 16) | (u1 & 0xFFFF0000u);
        o.u[d * 2 + 1] = (u2 >> 16) | (u3 & 0xFFFF0000u);
    }
    return o.v;
}

// ---------------- x prep: per-row i8 quant into strip-LDS-image order -------
// xq layout per strip (131072 B): byte (c*128 + r)*8 + j = x_i8[row r][k c*8+j]
// Block b: strip b>>1, rows [(b&1)*64, +64). Blocks 0..63 also init out=b2.
__global__ __launch_bounds__(512) void k_xprep(
    const float* __restrict__ x, const float* __restrict__ b2,
    unsigned char* __restrict__ xq, float* __restrict__ sx,
    float* __restrict__ out)
{
    const int bid = blockIdx.x;                 // 256
    const int strip = bid >> 1, rh = (bid & 1) * 64;
    const int wv = threadIdx.x >> 6, l = threadIdx.x & 63;
    unsigned char* dst = xq + (size_t)strip * 131072;

#pragma unroll 2
    for (int rr = 0; rr < 8; ++rr) {
        const int r = rh + wv * 8 + rr;         // row within strip
        const size_t gr = (size_t)strip * STRIP + r;
        const float* xr = x + gr * D_IN;
        nfloat4 v[4];
        float mx = 0.f;
#pragma unroll
        for (int i = 0; i < 4; ++i) {
            v[i] = *(const nfloat4*)(xr + i * 256 + l * 4);
            mx = fmaxf(mx, fmaxf(fmaxf(fabsf(v[i][0]), fabsf(v[i][1])),
                                 fmaxf(fabsf(v[i][2]), fabsf(v[i][3]))));
        }
#pragma unroll
        for (int m = 1; m <= 32; m <<= 1) mx = fmaxf(mx, __shfl_xor(mx, m, 64));
        const float qs = 127.0f / mx;
#pragma unroll
        for (int i = 0; i < 4; ++i) {
            int k0 = i * 256 + l * 4;
            int c = k0 >> 3, off = k0 & 7;
            unsigned pk = (unsigned)(__float2int_rn(v[i][0] * qs) & 255)
                        | ((unsigned)(__float2int_rn(v[i][1] * qs) & 255) << 8)
                        | ((unsigned)(__float2int_rn(v[i][2] * qs) & 255) << 16)
                        | ((unsigned)(__float2int_rn(v[i][3] * qs) & 255) << 24);
            *(unsigned*)(dst + c * 1024 + r * 8 + off) = pk;   // L2 merges lines
        }
        if (l == 0) sx[gr] = mx * (1.0f / 127.0f);
    }
    if (bid < 64 && threadIdx.x < 256)
        out[bid * 256 + threadIdx.x] = b2[0];
}

// ---------------- W prep: W_eff -> fragment-ordered bf16 (unchanged) --------
// short-offset n32*32768 + c*256 + rl*8 + j = W_eff[n32*32+rl][c*8+j]
__global__ __launch_bounds__(256) void k_wprep(
    const float* __restrict__ W0, const float* __restrict__ A,
    const float* __restrict__ Bl, unsigned short* __restrict__ wb)
{
    __shared__ unsigned short T[32][D_IN + 8];
    const int n32 = blockIdx.x;                   // 128 blocks
    const int t   = threadIdx.x;

    nfloat4 Areg[R_LORA];
#pragma unroll
    for (int j = 0; j < R_LORA; ++j)
        Areg[j] = *(const nfloat4*)(A + j * D_IN + t * 4);

#pragma unroll 4
    for (int r = 0; r < 32; ++r) {
        const int n = n32 * 32 + r;
        nfloat4 v = __builtin_nontemporal_load(
            (const nfloat4*)(W0 + (size_t)n * D_IN + t * 4));
        const float* brow = Bl + n * R_LORA;
#pragma unroll
        for (int j = 0; j < R_LORA; ++j)
            v = v + (SCALING * brow[j]) * Areg[j];
        ushort4 o = make_ushort4(f2bf(v[0]), f2bf(v[1]), f2bf(v[2]), f2bf(v[3]));
        *(ushort4*)(&T[r][t * 4]) = o;
    }
    __syncthreads();

    unsigned short* dstw = wb + (size_t)n32 * 32768;
#pragma unroll
    for (int i = 0; i < 16; ++i) {
        int L  = t * 128 + i * 8;
        int c  = L >> 8;
        int rl = (L >> 3) & 31;
        uint4 v = *(const uint4*)(&T[rl][c * 8]);
        *(uint4*)(dstw + L) = v;
    }
}

// ---------------- main fused kernel ----------------
__global__ __launch_bounds__(NTHREADS, 2) void k_strip(
    const unsigned char* __restrict__ xq, const float* __restrict__ sx,
    const unsigned short* __restrict__ wb,
    const float* __restrict__ b0, const float* __restrict__ W2,
    float* __restrict__ out)
{
    __shared__ unsigned char As[STRIP * D_IN];    // 128 KiB i8, (c*128+r)*8+j
    __shared__ float red[8][STRIP];               // 4 KiB cross-wave/pass acc
    __shared__ float sxs[STRIP];                  // per-row scales

    const int tid  = threadIdx.x;
    const int lane = tid & 63;
    const int wave = tid >> 6;
    const int rl   = lane & 31;
    const int half = lane >> 5;
    const int bid  = blockIdx.x;                  // 256
    const int strip = bid >> 1, h = bid & 1;      // parity == XCD parity
    const int row0 = strip * STRIP;

    // phase 0/1: zero red, load scales, DMA the prebuilt strip image into LDS
    {
        float* rp = &red[0][0];
        rp[tid] = 0.f;
        rp[tid + 512] = 0.f;
        if (tid < STRIP) sxs[tid] = sx[row0 + tid];
        const unsigned char* src = xq + (size_t)strip * 131072;
#pragma unroll
        for (int i = 0; i < 16; ++i) {
            int off = (i * NTHREADS + tid) * 16;
            __builtin_amdgcn_global_load_lds(
                (__attribute__((address_space(1))) void*)(src + off),
                (__attribute__((address_space(3))) void*)(&As[off]),
                16, 0, 0);
        }
    }
    __syncthreads();

    // main: 4 passes x 64 k-iters, zero barriers
    for (int pass = 0; pass < 4; ++pass) {
        const int n0 = h * 2048 + pass * 512 + wave * 64;
        const float w2a = W2[n0 + rl],      b0a = b0[n0 + rl];
        const float w2b = W2[n0 + 32 + rl], b0b = b0[n0 + 32 + rl];
        const unsigned short* wp = wb + (size_t)(n0 >> 5) * 32768 + half * 256 + rl * 8;

        f32x16 acc[4][2] = {};
        bf16x8 wf0[4], wf1[4];
#pragma unroll
        for (int p = 0; p < 4; ++p) {             // depth-4 rotation
            wf0[p] = *(const bf16x8*)(wp + p * 512);
            wf1[p] = *(const bf16x8*)(wp + 32768 + p * 512);
        }

#pragma unroll 4
        for (int kk = 0; kk < 64; ++kk) {
            const int cur = kk & 3;
            bf16x8 w0c = wf0[cur], w1c = wf1[cur];
            if (kk < 60) {
                wf0[cur] = *(const bf16x8*)(wp + (kk + 4) * 512);
                wf1[cur] = *(const bf16x8*)(wp + 32768 + (kk + 4) * 512);
            }
            // A: chunk c covers k=c*8..+8; row rt*32+rl; 8B each, expand to bf16
            const int c = kk * 2 + half;
            const unsigned char* ab = &As[c * 1024 + rl * 8];
            bf16x8 af[4];
#pragma unroll
            for (int rt = 0; rt < 4; ++rt) {
                int2 raw = *(const int2*)(ab + rt * 256);
                af[rt] = expand8(raw.x, raw.y);
            }
#pragma unroll
            for (int rt = 0; rt < 4; ++rt) {
                acc[rt][0] = __builtin_amdgcn_mfma_f32_32x32x16_bf16(af[rt], w0c, acc[rt][0], 0, 0, 0);
                acc[rt][1] = __builtin_amdgcn_mfma_f32_32x32x16_bf16(af[rt], w1c, acc[rt][1], 0, 0, 0);
            }
        }

        // pass fold: h = sx[row]*acc + b0; relu; dot W2; reduce 32 col-lanes
        // C/D layout (m74/m101): col = lane&31, row = (r&3)+8*(r>>2)+4*half
#pragma unroll
        for (int rt = 0; rt < 4; ++rt)
#pragma unroll
            for (int r = 0; r < 16; ++r) {
                const int row = rt * 32 + (r & 3) + 8 * (r >> 2) + 4 * half;
                const float s = sxs[row];
                float p = fmaxf(s * acc[rt][0][r] + b0a, 0.f) * w2a
                        + fmaxf(s * acc[rt][1][r] + b0b, 0.f) * w2b;
#pragma unroll
                for (int m = 1; m <= 16; m <<= 1)
                    p += __shfl_xor(p, m, 64);    // stays within each 32-half
                if (rl == 0) red[wave][row] += p;
            }
    }

    __syncthreads();
    if (tid < STRIP) {
        float s = 0.f;
#pragma unroll
        for (int w = 0; w < 8; ++w) s += red[w][tid];
        unsafeAtomicAdd(&out[row0 + tid], s);     // out pre-init to b2 (xprep)
    }
}

// ---------------- naive fallback (correctness only; ws too small) -----------
__global__ __launch_bounds__(256) void k_naive(
    const float* __restrict__ x, const float* __restrict__ W0,
    const float* __restrict__ b0, const float* __restrict__ A,
    const float* __restrict__ Bl, const float* __restrict__ W2,
    const float* __restrict__ b2, float* __restrict__ out)
{
    __shared__ float xs[D_IN];
    int b = blockIdx.x;
    for (int d = threadIdx.x; d < D_IN; d += 256) xs[d] = x[(size_t)b * D_IN + d];
    __syncthreads();
    float part = 0.f;
    for (int m = threadIdx.x; m < M_HID; m += 256) {
        float hh = b0[m];
        const float* wr = W0 + (size_t)m * D_IN;
        const float* brow = Bl + m * R_LORA;
        for (int d = 0; d < D_IN; ++d) {
            float w = wr[d];
            for (int r = 0; r < R_LORA; ++r) w += SCALING * brow[r] * A[r * D_IN + d];
            hh += xs[d] * w;
        }
        part += fmaxf(hh, 0.f) * W2[m];
    }
    __shared__ float sred[256];
    sred[threadIdx.x] = part;
    __syncthreads();
    for (int s = 128; s > 0; s >>= 1) {
        if (threadIdx.x < s) sred[threadIdx.x] += sred[threadIdx.x + s];
        __syncthreads();
    }
    if (threadIdx.x == 0) out[b] = sred[0] + b2[0];
}

// ---------------- host ----------------
extern "C" void kernel_launch(void* const* d_in, const int* in_sizes, int n_in,
                              void* d_out, int out_size, void* d_ws, size_t ws_size,
                              hipStream_t stream) {
    const float* x  = (const float*)d_in[0];
    const float* W0 = (const float*)d_in[1];
    const float* b0 = (const float*)d_in[2];
    const float* A  = (const float*)d_in[3];
    const float* Bl = (const float*)d_in[4];
    const float* W2 = (const float*)d_in[5];
    const float* b2 = (const float*)d_in[6];
    float* out = (float*)d_out;

    const size_t xq_bytes = (size_t)BATCH * D_IN;        // 16 MiB i8
    const size_t sx_bytes = (size_t)BATCH * 4;           // 64 KiB
    const size_t wb_bytes = (size_t)M_HID * D_IN * 2;    // 8 MiB
    if (ws_size >= xq_bytes + sx_bytes + wb_bytes) {
        unsigned char*  xq = (unsigned char*)d_ws;
        float*          sx = (float*)((char*)d_ws + xq_bytes);
        unsigned short* wb = (unsigned short*)((char*)d_ws + xq_bytes + sx_bytes);
        hipLaunchKernelGGL(k_xprep, dim3(256), dim3(512), 0, stream, x, b2, xq, sx, out);
        hipLaunchKernelGGL(k_wprep, dim3(M_HID / 32), dim3(256), 0, stream, W0, A, Bl, wb);
        hipLaunchKernelGGL(k_strip, dim3(256), dim3(NTHREADS), 0, stream,
                           xq, sx, wb, b0, W2, out);
    } else {
        hipLaunchKernelGGL(k_naive, dim3(BATCH), dim3(256), 0, stream,
                           x, W0, b0, A, Bl, W2, b2, out);
    }
}

// Round 10
// 291.560 us; speedup vs baseline: 1.1501x; 1.1501x over previous
//
#include <hip/hip_runtime.h>
#include <hip/hip_bf16.h>
#include <stdint.h>

// Problem constants (fixed by the reference setup_inputs)
#define BATCH  16384
#define D_IN   1024
#define M_HID  4096
#define R_LORA 16
#define SCALING 2.0f   // ALPHA/R = 32/16

// R10: i8 x i8 MFMA (mfma_i32_32x32x32_i8, 2x bf16 rate). R9 failed on the
// i8->bf16 VALU expand (VALUBusy 44.6% serialized the MFMA stream). Now both
// operands are i8: no expand, W-stream halves to 2 MB/CU (at the measured
// ~22 B/cyc/CU VMEM wall -> 40 us floor), MFMA floor 31 us. Dequant is the
// exact rank-1 fixup sx[row]*sw[n]*acc in the epilogue. A/B frag layout:
// lane rl = row/col, k = (lane>>5)*16 + j (16 contiguous bytes/lane),
// extrapolating the HW-verified bf16 32x32x16 pattern; C/D layout is
// shape-determined (m121-128, incl. i8).
#define STRIP    128
#define NTHREADS 512

typedef int    i32x4  __attribute__((ext_vector_type(4)));
typedef int    i32x16 __attribute__((ext_vector_type(16)));
typedef float  nfloat4 __attribute__((ext_vector_type(4)));

// ---------------- x prep: per-row i8 quant into strip-LDS-image order -------
// Image per strip (131072 B): byte (c16*128 + r)*16 + j = x_i8[r][k=c16*16+j]
__global__ __launch_bounds__(512) void k_xprep(
    const float* __restrict__ x, unsigned char* __restrict__ xq,
    float* __restrict__ sx)
{
    const int bid = blockIdx.x;                 // 256
    const int strip = bid >> 1, rh = (bid & 1) * 64;
    const int wv = threadIdx.x >> 6, l = threadIdx.x & 63;
    unsigned char* dst = xq + (size_t)strip * 131072;

#pragma unroll 2
    for (int rr = 0; rr < 8; ++rr) {
        const int r = rh + wv * 8 + rr;         // row within strip
        const size_t gr = (size_t)strip * STRIP + r;
        const float* xr = x + gr * D_IN;
        nfloat4 v[4];
        float mx = 1e-30f;
#pragma unroll
        for (int i = 0; i < 4; ++i) {
            v[i] = __builtin_nontemporal_load((const nfloat4*)(xr + i * 256 + l * 4));
            mx = fmaxf(mx, fmaxf(fmaxf(fabsf(v[i][0]), fabsf(v[i][1])),
                                 fmaxf(fabsf(v[i][2]), fabsf(v[i][3]))));
        }
#pragma unroll
        for (int m = 1; m <= 32; m <<= 1) mx = fmaxf(mx, __shfl_xor(mx, m, 64));
        const float qs = 127.0f / mx;
#pragma unroll
        for (int i = 0; i < 4; ++i) {
            int c16 = i * 16 + (l >> 2);        // k0 = i*256 + l*4; c16 = k0>>4
            int j   = (l & 3) * 4;
            unsigned pk = (unsigned)(__float2int_rn(v[i][0] * qs) & 255)
                        | ((unsigned)(__float2int_rn(v[i][1] * qs) & 255) << 8)
                        | ((unsigned)(__float2int_rn(v[i][2] * qs) & 255) << 16)
                        | ((unsigned)(__float2int_rn(v[i][3] * qs) & 255) << 24);
            *(unsigned*)(dst + c16 * 2048 + r * 16 + j) = pk;
        }
        if (l == 0) sx[gr] = mx * (1.0f / 127.0f);
    }
}

// ---------------- W prep: W_eff -> per-col i8, fragment order ----------------
// wq per 32-n group (32768 B): byte (c16*32 + rl)*16 + j = Wq[n=g*32+rl][k=c16*16+j]
// Blocks 128..191: out[b] = b2[0] (pre-init for strip atomics).
__global__ __launch_bounds__(256, 1) void k_wprep(
    const float* __restrict__ W0, const float* __restrict__ A,
    const float* __restrict__ Bl, const float* __restrict__ b2,
    signed char* __restrict__ wq, float* __restrict__ sw,
    float* __restrict__ out)
{
    const int bid = blockIdx.x;
    if (bid >= 128) {
        int i = (bid - 128) * 256 + threadIdx.x;
        out[i] = b2[0];
        return;
    }
    __shared__ int imax[32];
    __shared__ signed char T2[32][D_IN + 16];     // 16B pad, rows 16B-aligned
    const int n32 = bid, t = threadIdx.x;
    if (t < 32) imax[t] = 0;

    nfloat4 Areg[R_LORA];
#pragma unroll
    for (int j = 0; j < R_LORA; ++j)
        Areg[j] = *(const nfloat4*)(A + j * D_IN + t * 4);
    __syncthreads();

    // phase A: W_eff rows into registers + per-row max (wave-reduce + LDS atomic)
    nfloat4 vrow[32];
#pragma unroll 4
    for (int r = 0; r < 32; ++r) {
        const int n = n32 * 32 + r;
        nfloat4 v = __builtin_nontemporal_load(
            (const nfloat4*)(W0 + (size_t)n * D_IN + t * 4));
        const float* brow = Bl + n * R_LORA;
#pragma unroll
        for (int j = 0; j < R_LORA; ++j)
            v = v + (SCALING * brow[j]) * Areg[j];
        vrow[r] = v;
        float m = fmaxf(fmaxf(fabsf(v[0]), fabsf(v[1])),
                        fmaxf(fabsf(v[2]), fabsf(v[3])));
        m = fmaxf(m, 1e-30f);
#pragma unroll
        for (int s = 1; s <= 32; s <<= 1) m = fmaxf(m, __shfl_xor(m, s, 64));
        if ((t & 63) == 0) atomicMax(&imax[r], __float_as_int(m));
    }
    __syncthreads();

    // phase B: quantize from registers into LDS row-major
#pragma unroll 4
    for (int r = 0; r < 32; ++r) {
        const float qs = 127.0f / __int_as_float(imax[r]);
        nfloat4 v = vrow[r];
        unsigned pk = (unsigned)(__float2int_rn(v[0] * qs) & 255)
                    | ((unsigned)(__float2int_rn(v[1] * qs) & 255) << 8)
                    | ((unsigned)(__float2int_rn(v[2] * qs) & 255) << 16)
                    | ((unsigned)(__float2int_rn(v[3] * qs) & 255) << 24);
        *(unsigned*)(&T2[r][t * 4]) = pk;
    }
    if (t < 32) sw[n32 * 32 + t] = __int_as_float(imax[t]) * (1.0f / 127.0f);
    __syncthreads();

    // write out fragment-ordered; lanes contiguous per c16 iter (coalesced)
    signed char* dst = wq + (size_t)n32 * 32768;
    const int r = t & 31, c0 = (t >> 5) * 8;
#pragma unroll
    for (int i = 0; i < 8; ++i) {
        int c16 = c0 + i;
        uint4 v = *(const uint4*)(&T2[r][c16 * 16]);
        *(uint4*)(dst + (c16 * 32 + r) * 16) = v;
    }
}

// ---------------- main fused kernel ----------------
__global__ __launch_bounds__(NTHREADS, 2) void k_strip(
    const unsigned char* __restrict__ xq, const float* __restrict__ sx,
    const signed char* __restrict__ wq, const float* __restrict__ sw,
    const float* __restrict__ b0, const float* __restrict__ W2,
    float* __restrict__ out)
{
    __shared__ unsigned char As[STRIP * D_IN];    // 128 KiB i8 strip image
    __shared__ float red[8][STRIP];               // 4 KiB cross-wave/pass acc
    __shared__ float sxs[STRIP];

    const int tid  = threadIdx.x;
    const int lane = tid & 63;
    const int wave = tid >> 6;
    const int rl   = lane & 31;
    const int half = lane >> 5;
    const int bid  = blockIdx.x;                  // 256
    const int strip = bid >> 1, h = bid & 1;      // all blocks on XCD j share parity j&1
    const int row0 = strip * STRIP;

    {   // zero red, load scales, DMA strip image into LDS
        float* rp = &red[0][0];
        rp[tid] = 0.f;
        rp[tid + 512] = 0.f;
        if (tid < STRIP) sxs[tid] = sx[row0 + tid];
        const unsigned char* src = xq + (size_t)strip * 131072;
#pragma unroll
        for (int i = 0; i < 16; ++i) {
            int off = (i * NTHREADS + tid) * 16;
            __builtin_amdgcn_global_load_lds(
                (__attribute__((address_space(1))) void*)(src + off),
                (__attribute__((address_space(3))) void*)(&As[off]),
                16, 0, 0);
        }
    }
    __syncthreads();

    // main: 4 passes x 32 k-iters (K-step 32), zero barriers
    for (int pass = 0; pass < 4; ++pass) {
        const int n0 = h * 2048 + pass * 512 + wave * 64;
        const float w2a = W2[n0 + rl],      b0a = b0[n0 + rl];
        const float w2b = W2[n0 + 32 + rl], b0b = b0[n0 + 32 + rl];
        const float swa = sw[n0 + rl],      swb = sw[n0 + 32 + rl];
        const signed char* wp = wq + (size_t)(n0 >> 5) * 32768 + rl * 16;

        i32x16 acc[4][2] = {};
        i32x4 wf0[4], wf1[4];
#pragma unroll
        for (int p = 0; p < 4; ++p) {             // depth-4 rotation
            wf0[p] = *(const i32x4*)(wp + (p * 2 + half) * 512);
            wf1[p] = *(const i32x4*)(wp + 32768 + (p * 2 + half) * 512);
        }

#pragma unroll 4
        for (int kk = 0; kk < 32; ++kk) {
            const int cur = kk & 3;
            i32x4 w0c = wf0[cur], w1c = wf1[cur];
            if (kk < 28) {
                wf0[cur] = *(const i32x4*)(wp + ((kk + 4) * 2 + half) * 512);
                wf1[cur] = *(const i32x4*)(wp + 32768 + ((kk + 4) * 2 + half) * 512);
            }
            const int c16 = kk * 2 + half;
            const unsigned char* ab = &As[c16 * 2048 + rl * 16];
            i32x4 af[4];
#pragma unroll
            for (int rt = 0; rt < 4; ++rt)
                af[rt] = *(const i32x4*)(ab + rt * 512);
#pragma unroll
            for (int rt = 0; rt < 4; ++rt) {
                acc[rt][0] = __builtin_amdgcn_mfma_i32_32x32x32_i8(af[rt], w0c, acc[rt][0], 0, 0, 0);
                acc[rt][1] = __builtin_amdgcn_mfma_i32_32x32x32_i8(af[rt], w1c, acc[rt][1], 0, 0, 0);
            }
        }

        // fold: h = sx[row]*sw[n]*acc + b0; relu; dot W2; reduce 32 col-lanes
        // C/D layout (m74/m101, dtype-indep m121-128): col=lane&31,
        // row = (r&3) + 8*(r>>2) + 4*half
#pragma unroll
        for (int rt = 0; rt < 4; ++rt)
#pragma unroll
            for (int r = 0; r < 16; ++r) {
                const int row = rt * 32 + (r & 3) + 8 * (r >> 2) + 4 * half;
                const float s = sxs[row];
                float p = fmaxf(s * swa * (float)acc[rt][0][r] + b0a, 0.f) * w2a
                        + fmaxf(s * swb * (float)acc[rt][1][r] + b0b, 0.f) * w2b;
#pragma unroll
                for (int m = 1; m <= 16; m <<= 1)
                    p += __shfl_xor(p, m, 64);    // stays within each 32-half
                if (rl == 0) red[wave][row] += p;
            }
    }

    __syncthreads();
    if (tid < STRIP) {
        float s = 0.f;
#pragma unroll
        for (int w = 0; w < 8; ++w) s += red[w][tid];
        unsafeAtomicAdd(&out[row0 + tid], s);     // out pre-init to b2 (wprep)
    }
}

// ---------------- naive fallback (correctness only; ws too small) -----------
__global__ __launch_bounds__(256) void k_naive(
    const float* __restrict__ x, const float* __restrict__ W0,
    const float* __restrict__ b0, const float* __restrict__ A,
    const float* __restrict__ Bl, const float* __restrict__ W2,
    const float* __restrict__ b2, float* __restrict__ out)
{
    __shared__ float xs[D_IN];
    int b = blockIdx.x;
    for (int d = threadIdx.x; d < D_IN; d += 256) xs[d] = x[(size_t)b * D_IN + d];
    __syncthreads();
    float part = 0.f;
    for (int m = threadIdx.x; m < M_HID; m += 256) {
        float hh = b0[m];
        const float* wr = W0 + (size_t)m * D_IN;
        const float* brow = Bl + m * R_LORA;
        for (int d = 0; d < D_IN; ++d) {
            float w = wr[d];
            for (int r = 0; r < R_LORA; ++r) w += SCALING * brow[r] * A[r * D_IN + d];
            hh += xs[d] * w;
        }
        part += fmaxf(hh, 0.f) * W2[m];
    }
    __shared__ float sred[256];
    sred[threadIdx.x] = part;
    __syncthreads();
    for (int s = 128; s > 0; s >>= 1) {
        if (threadIdx.x < s) sred[threadIdx.x] += sred[threadIdx.x + s];
        __syncthreads();
    }
    if (threadIdx.x == 0) out[b] = sred[0] + b2[0];
}

// ---------------- host ----------------
extern "C" void kernel_launch(void* const* d_in, const int* in_sizes, int n_in,
                              void* d_out, int out_size, void* d_ws, size_t ws_size,
                              hipStream_t stream) {
    const float* x  = (const float*)d_in[0];
    const float* W0 = (const float*)d_in[1];
    const float* b0 = (const float*)d_in[2];
    const float* A  = (const float*)d_in[3];
    const float* Bl = (const float*)d_in[4];
    const float* W2 = (const float*)d_in[5];
    const float* b2 = (const float*)d_in[6];
    float* out = (float*)d_out;

    const size_t xq_bytes = (size_t)BATCH * D_IN;        // 16 MiB i8
    const size_t sx_bytes = (size_t)BATCH * 4;           // 64 KiB
    const size_t wq_bytes = (size_t)M_HID * D_IN;        // 4 MiB i8
    const size_t sw_bytes = (size_t)M_HID * 4;           // 16 KiB
    if (ws_size >= xq_bytes + sx_bytes + wq_bytes + sw_bytes) {
        unsigned char* xq = (unsigned char*)d_ws;
        float*         sx = (float*)((char*)d_ws + xq_bytes);
        signed char*   wq = (signed char*)((char*)d_ws + xq_bytes + sx_bytes);
        float*         sw = (float*)((char*)d_ws + xq_bytes + sx_bytes + wq_bytes);
        hipLaunchKernelGGL(k_xprep, dim3(256), dim3(512), 0, stream, x, xq, sx);
        hipLaunchKernelGGL(k_wprep, dim3(192), dim3(256), 0, stream,
                           W0, A, Bl, b2, wq, sw, out);
        hipLaunchKernelGGL(k_strip, dim3(256), dim3(NTHREADS), 0, stream,
                           xq, sx, wq, sw, b0, W2, out);
    } else {
        hipLaunchKernelGGL(k_naive, dim3(BATCH), dim3(256), 0, stream,
                           x, W0, b0, A, Bl, W2, b2, out);
    }
}